// Round 4
// baseline (1271.349 us; speedup 1.0000x reference)
//
#include <hip/hip_runtime.h>

#define NN 200000
#define NE 600000
#define NG 8192
#define HD 128
#define FIN 7
#define BN_EPS 1e-5f

#define CHUNK 1024
#define NB 196          // ceil(NN / CHUNK)
#define TAX 160         // nodes per aggx tile (200000 = 160*1250)
#define NBAX 1250

// ---------------- merged degree + graph-count histogram ----------------
__global__ void k_hist(const int* __restrict__ dstC, const int* __restrict__ dstS,
                       const int* __restrict__ batchC, const int* __restrict__ batchS,
                       int* __restrict__ degC, int* __restrict__ degS,
                       int* __restrict__ cntC, int* __restrict__ cntS) {
    int e = blockIdx.x * 256 + threadIdx.x;
    if (e < NE)            atomicAdd(&degC[dstC[e]], 1);
    else if (e < 2 * NE)   atomicAdd(&degS[dstS[e - NE]], 1);
    if (e < NN)                      atomicAdd(&cntC[batchC[e]], 1);
    else if (e >= NE && e < NE + NN) atomicAdd(&cntS[batchS[e - NE]], 1);
}

// ---------------- merged 3-phase exclusive scan (dinv folded into phase 1) ----------------
__global__ void k_scan1m(const int* __restrict__ degC, const int* __restrict__ degS,
                         int* __restrict__ bsumC, int* __restrict__ bsumS,
                         float* __restrict__ dinvC, float* __restrict__ dinvS) {
    __shared__ int sd[256];
    int t = threadIdx.x;
    int b = blockIdx.x;
    bool sBr = b >= NB;
    int bb = sBr ? b - NB : b;
    const int* deg = sBr ? degS : degC;
    float* dinv = sBr ? dinvS : dinvC;
    int* bsum = sBr ? bsumS : bsumC;
    int base = bb * CHUNK + t * 4;
    int s = 0;
#pragma unroll
    for (int j = 0; j < 4; j++) {
        int i = base + j;
        if (i < NN) {
            int d = deg[i];
            s += d;
            dinv[i] = rsqrtf((float)(d + 1));
        }
    }
    sd[t] = s; __syncthreads();
    for (int st = 128; st > 0; st >>= 1) { if (t < st) sd[t] += sd[t + st]; __syncthreads(); }
    if (t == 0) bsum[bb] = sd[0];
}

__global__ void k_scan2m(int* __restrict__ bsumC, int* __restrict__ bsumS) {
    __shared__ int sd[256];
    int* bsum = blockIdx.x ? bsumS : bsumC;
    int t = threadIdx.x;
    int v = (t < NB) ? bsum[t] : 0;
    sd[t] = v; __syncthreads();
    for (int st = 1; st < 256; st <<= 1) {
        int add = (t >= st) ? sd[t - st] : 0;
        __syncthreads();
        sd[t] += add;
        __syncthreads();
    }
    if (t < NB) bsum[t] = sd[t] - v;   // exclusive
}

__global__ void k_scan3m(const int* __restrict__ degC, const int* __restrict__ degS,
                         const int* __restrict__ bsumC, const int* __restrict__ bsumS,
                         int* __restrict__ offsC, int* __restrict__ offsS,
                         int* __restrict__ curC, int* __restrict__ curS) {
    __shared__ int sd[256];
    int t = threadIdx.x;
    int b = blockIdx.x;
    bool sBr = b >= NB;
    int bb = sBr ? b - NB : b;
    const int* deg  = sBr ? degS  : degC;
    const int* bsum = sBr ? bsumS : bsumC;
    int* offs   = sBr ? offsS : offsC;
    int* cursor = sBr ? curS  : curC;
    int base = bb * CHUNK + t * 4;
    int v[4]; int s = 0;
#pragma unroll
    for (int j = 0; j < 4; j++) { int i = base + j; v[j] = (i < NN) ? deg[i] : 0; s += v[j]; }
    sd[t] = s; __syncthreads();
    for (int st = 1; st < 256; st <<= 1) {
        int add = (t >= st) ? sd[t - st] : 0;
        __syncthreads();
        sd[t] += add;
        __syncthreads();
    }
    int run = bsum[bb] + sd[t] - s;
#pragma unroll
    for (int j = 0; j < 4; j++) {
        int i = base + j;
        if (i < NN) { offs[i] = run; cursor[i] = run; run += v[j]; }
    }
    if (bb == 0 && t == 0) offs[NN] = NE;
}

__global__ void k_fillm(const int* __restrict__ srcC, const int* __restrict__ dstC,
                        const int* __restrict__ srcS, const int* __restrict__ dstS,
                        int* __restrict__ curC, int* __restrict__ curS,
                        int* __restrict__ csrC, int* __restrict__ csrS) {
    int e = blockIdx.x * 256 + threadIdx.x;
    if (e < NE) {
        int d = dstC[e];
        int pos = atomicAdd(&curC[d], 1);
        csrC[pos] = srcC[e];
    } else if (e < 2 * NE) {
        int ee = e - NE;
        int d = dstS[ee];
        int pos = atomicAdd(&curS[d], 1);
        csrS[pos] = srcS[ee];
    }
}

// ---------------- xs = dinv * x, padded to 8 floats/row ----------------
__global__ void k_prex(const float* __restrict__ xC, const float* __restrict__ xS,
                       const float* __restrict__ dinvC, const float* __restrict__ dinvS,
                       float* __restrict__ xsC, float* __restrict__ xsS) {
    int gid = blockIdx.x * 256 + threadIdx.x;    // 2*NN*8 threads (12500 blocks exact)
    bool sBr = gid >= NN * 8;
    int lid = sBr ? gid - NN * 8 : gid;
    const float* x    = sBr ? xS    : xC;
    const float* dinv = sBr ? dinvS : dinvC;
    float*       xs   = sBr ? xsS   : xsC;
    int i = lid >> 3, f = lid & 7;
    float v = (f < FIN) ? x[(size_t)i * FIN + f] : 0.f;
    xs[lid] = v * dinv[i];
}

// ---------------- layer-1 aggregation: edge-parallel tile gather ----------------
// ax[i] = dinv_i * (xs[i] + sum_{s in N(i)} xs[s]),  xs pre-scaled by dinv_s
__global__ __launch_bounds__(256) void k_aggx2(
    const float* __restrict__ xsC, const float* __restrict__ xsS,
    const float* __restrict__ dinvC, const float* __restrict__ dinvS,
    const int* __restrict__ offsC, const int* __restrict__ offsS,
    const int* __restrict__ csrC, const int* __restrict__ csrS,
    float* __restrict__ axC, float* __restrict__ axS)
{
    __shared__ float sax[TAX * 8];
    __shared__ int soffs[TAX + 1];
    __shared__ float sdinv[TAX];
    int b = blockIdx.x;
    bool sBr = b >= NBAX;
    int bb = sBr ? b - NBAX : b;
    const float* xs   = sBr ? xsS   : xsC;
    const float* dinv = sBr ? dinvS : dinvC;
    const int*   offs = sBr ? offsS : offsC;
    const int*   csr  = sBr ? csrS  : csrC;
    float*       ax   = sBr ? axS   : axC;
    int t = threadIdx.x;
    int nbase = bb * TAX;
    if (t <= TAX) soffs[t] = offs[nbase + t];
    if (t < TAX) sdinv[t] = dinv[nbase + t];
#pragma unroll
    for (int r = 0; r < 5; r++) {                // self term: 5*256 = TAX*8
        int idx = r * 256 + t;
        sax[idx] = xs[(size_t)nbase * 8 + idx];
    }
    __syncthreads();
    int E0 = soffs[0], E1 = soffs[TAX];
    int Et = E1 - E0;
    int f = t & 7, eg = t >> 3;                  // 32 edge groups x 8 feature lanes
    int len = (Et + 31) >> 5;
    int e = E0 + eg * len;
    int eend = min(e + len, E1);
    if (e < eend) {
        int lo = 0, hi = TAX;                    // initial search for this range's first dst
        while (hi - lo > 1) { int m = (lo + hi) >> 1; if (e >= soffs[m]) lo = m; else hi = m; }
        for (; e < eend; e++) {
            int s = csr[e];
            float v = xs[(size_t)s * 8 + f];
            while (e >= soffs[lo + 1]) ++lo;     // incremental dst advance
            atomicAdd(&sax[lo * 8 + f], v);
        }
    }
    __syncthreads();
#pragma unroll
    for (int r = 0; r < 5; r++) {
        int idx = r * 256 + t;
        ax[(size_t)nbase * 8 + idx] = sax[idx] * sdinv[idx >> 3];
    }
}

// ---------------- layer-1 GEMM + BN + ReLU, output pre-scaled by dinv ----------------
__global__ __launch_bounds__(256) void k_gemm1m(
    const float* __restrict__ ax, const float* __restrict__ dinv,
    const float* __restrict__ W0, const float* __restrict__ b0,
    const float* __restrict__ gamma, const float* __restrict__ beta,
    const float* __restrict__ mean, const float* __restrict__ var,
    float* __restrict__ h1s)
{
    int gid = blockIdx.x * 256 + threadIdx.x;   // NN*32 threads (25000 blocks exact)
    int i = gid >> 5, q = (gid & 31) * 4;
    float4 a0 = *reinterpret_cast<const float4*>(&ax[(size_t)i * 8]);
    float4 a1 = *reinterpret_cast<const float4*>(&ax[(size_t)i * 8 + 4]);
    float axr[7] = { a0.x, a0.y, a0.z, a0.w, a1.x, a1.y, a1.z };
    float4 acc = *reinterpret_cast<const float4*>(&b0[q]);
#pragma unroll
    for (int k = 0; k < FIN; k++) {
        float4 w = *reinterpret_cast<const float4*>(&W0[k * HD + q]);
        acc.x = fmaf(axr[k], w.x, acc.x);
        acc.y = fmaf(axr[k], w.y, acc.y);
        acc.z = fmaf(axr[k], w.z, acc.z);
        acc.w = fmaf(axr[k], w.w, acc.w);
    }
    float di = dinv[i];
    float4 gm = *reinterpret_cast<const float4*>(&gamma[q]);
    float4 bt = *reinterpret_cast<const float4*>(&beta[q]);
    float4 mn = *reinterpret_cast<const float4*>(&mean[q]);
    float4 vr = *reinterpret_cast<const float4*>(&var[q]);
    float4 o;
    o.x = fmaxf((acc.x - mn.x) * (gm.x * rsqrtf(vr.x + BN_EPS)) + bt.x, 0.f) * di;
    o.y = fmaxf((acc.y - mn.y) * (gm.y * rsqrtf(vr.y + BN_EPS)) + bt.y, 0.f) * di;
    o.z = fmaxf((acc.z - mn.z) * (gm.z * rsqrtf(vr.z + BN_EPS)) + bt.z, 0.f) * di;
    o.w = fmaxf((acc.w - mn.w) * (gm.w * rsqrtf(vr.w + BN_EPS)) + bt.w, 0.f) * di;
    *reinterpret_cast<float4*>(&h1s[(size_t)i * HD + q]) = o;
}

// ---------------- fused: edge-parallel gather -> LDS, GEMM W1, BN+ReLU, mean-pool ----------------
__global__ __launch_bounds__(256, 4) void k_agp(
    const float* __restrict__ h1s, const float* __restrict__ dinv,
    const int* __restrict__ offs, const int* __restrict__ csr,
    const int* __restrict__ batch,
    const float* __restrict__ W1, const float* __restrict__ b1,
    const float* __restrict__ gamma, const float* __restrict__ beta,
    const float* __restrict__ mean, const float* __restrict__ var,
    float* __restrict__ pool)
{
    __shared__ float g2[64][132];
    __shared__ int soffs[65];
    __shared__ float sdinv[64];
    int t = threadIdx.x;
    int nbase = blockIdx.x * 64;                 // 3125 blocks exact
    if (t <= 64) soffs[t] = offs[nbase + t];
    else if (t >= 128 && t < 192) sdinv[t - 128] = dinv[nbase + t - 128];
    int q = t & 31, ng = t >> 5;

    // ---- phase 1a: self term (strided feature layout: f = q + 32k) ----
#pragma unroll
    for (int n = 0; n < 8; n++) {
        int node = ng * 8 + n;
        const float* row = &h1s[(size_t)(nbase + node) * HD + q];
        g2[node][q]      = row[0];
        g2[node][q + 32] = row[32];
        g2[node][q + 64] = row[64];
        g2[node][q + 96] = row[96];
    }
    __syncthreads();

    // ---- phase 1b: edge-parallel neighbor accumulation ----
    {
        int E0 = soffs[0], E1 = soffs[64];
        int Et = E1 - E0;
        int len = (Et + 7) >> 3;
        int e = E0 + ng * len;
        int eend = min(e + len, E1);
        if (e < eend) {
            int lo = 0, hi = 64;
            while (hi - lo > 1) { int m = (lo + hi) >> 1; if (e >= soffs[m]) lo = m; else hi = m; }
            for (; e < eend; e++) {
                int s = csr[e];
                const float* r = &h1s[(size_t)s * HD + q];
                float v0 = r[0], v1 = r[32], v2 = r[64], v3 = r[96];
                while (e >= soffs[lo + 1]) ++lo;
                atomicAdd(&g2[lo][q],      v0);
                atomicAdd(&g2[lo][q + 32], v1);
                atomicAdd(&g2[lo][q + 64], v2);
                atomicAdd(&g2[lo][q + 96], v3);
            }
        }
    }
    __syncthreads();

    // ---- phase 2: GEMM (64x128 @ 128x128), thread = 8 nodes x 4 features ----
    int f0 = q * 4, n0 = ng * 8;
    float acc[8][4];
#pragma unroll
    for (int a = 0; a < 8; a++)
#pragma unroll
        for (int c = 0; c < 4; c++) acc[a][c] = 0.f;

    for (int k = 0; k < 128; k += 4) {
        float ha[8][4];
#pragma unroll
        for (int a = 0; a < 8; a++) {
            float4 hv = *reinterpret_cast<const float4*>(&g2[n0 + a][k]);
            ha[a][0] = hv.x; ha[a][1] = hv.y; ha[a][2] = hv.z; ha[a][3] = hv.w;
        }
#pragma unroll
        for (int j = 0; j < 4; j++) {
            float4 w = *reinterpret_cast<const float4*>(&W1[(k + j) * HD + f0]);
#pragma unroll
            for (int a = 0; a < 8; a++) {
                acc[a][0] = fmaf(ha[a][j], w.x, acc[a][0]);
                acc[a][1] = fmaf(ha[a][j], w.y, acc[a][1]);
                acc[a][2] = fmaf(ha[a][j], w.z, acc[a][2]);
                acc[a][3] = fmaf(ha[a][j], w.w, acc[a][3]);
            }
        }
    }

    // ---- phase 3: scale by dinv_i, BN + ReLU + segmented mean-pool ----
    float4 gm = *reinterpret_cast<const float4*>(&gamma[f0]);
    float4 bt = *reinterpret_cast<const float4*>(&beta[f0]);
    float4 mn = *reinterpret_cast<const float4*>(&mean[f0]);
    float4 vr = *reinterpret_cast<const float4*>(&var[f0]);
    float4 bb = *reinterpret_cast<const float4*>(&b1[f0]);
    float Ax = gm.x * rsqrtf(vr.x + BN_EPS), Bx = (bb.x - mn.x) * Ax + bt.x;
    float Ay = gm.y * rsqrtf(vr.y + BN_EPS), By = (bb.y - mn.y) * Ay + bt.y;
    float Az = gm.z * rsqrtf(vr.z + BN_EPS), Bz = (bb.z - mn.z) * Az + bt.z;
    float Aw = gm.w * rsqrtf(vr.w + BN_EPS), Bw = (bb.w - mn.w) * Aw + bt.w;

    float sx = 0, sy = 0, sz = 0, sw = 0;
    int curg = -1;
#pragma unroll
    for (int a = 0; a < 8; a++) {
        int i = nbase + n0 + a;
        int g = batch[i];
        float sdv = sdinv[n0 + a];
        float zx = fmaxf(fmaf(acc[a][0] * sdv, Ax, Bx), 0.f);
        float zy = fmaxf(fmaf(acc[a][1] * sdv, Ay, By), 0.f);
        float zz = fmaxf(fmaf(acc[a][2] * sdv, Az, Bz), 0.f);
        float zw = fmaxf(fmaf(acc[a][3] * sdv, Aw, Bw), 0.f);
        if (g != curg) {
            if (curg >= 0) {
                atomicAdd(&pool[curg * HD + f0 + 0], sx);
                atomicAdd(&pool[curg * HD + f0 + 1], sy);
                atomicAdd(&pool[curg * HD + f0 + 2], sz);
                atomicAdd(&pool[curg * HD + f0 + 3], sw);
            }
            curg = g; sx = zx; sy = zy; sz = zz; sw = zw;
        } else { sx += zx; sy += zy; sz += zz; sw += zw; }
    }
    atomicAdd(&pool[curg * HD + f0 + 0], sx);
    atomicAdd(&pool[curg * HD + f0 + 1], sy);
    atomicAdd(&pool[curg * HD + f0 + 2], sz);
    atomicAdd(&pool[curg * HD + f0 + 3], sw);
}

// ---------------- final MLP, 8 graphs per block ----------------
#define GPB 8
__global__ __launch_bounds__(128) void k_mlp(
    const float* __restrict__ pc, const float* __restrict__ ps,
    const int* __restrict__ cc, const int* __restrict__ cs,
    const float* __restrict__ w1, const float* __restrict__ b1,
    const float* __restrict__ w2, const float* __restrict__ b2,
    float* __restrict__ outp)
{
    __shared__ float xc[GPB][256];
    __shared__ float hb[GPB][128];
    int t = threadIdx.x;
    int g0 = blockIdx.x * GPB;
#pragma unroll
    for (int gg = 0; gg < GPB; gg++) {
        int g = g0 + gg;
        xc[gg][t]       = pc[g * HD + t] / fmaxf((float)cc[g], 1.f);
        xc[gg][128 + t] = ps[g * HD + t] / fmaxf((float)cs[g], 1.f);
    }
    __syncthreads();
    float acc[GPB];
#pragma unroll
    for (int gg = 0; gg < GPB; gg++) acc[gg] = b1[t];
#pragma unroll 4
    for (int k = 0; k < 256; k++) {
        float w = w1[k * HD + t];
#pragma unroll
        for (int gg = 0; gg < GPB; gg++) acc[gg] = fmaf(xc[gg][k], w, acc[gg]);
    }
#pragma unroll
    for (int gg = 0; gg < GPB; gg++) hb[gg][t] = fmaxf(acc[gg], 0.f);
    __syncthreads();
    if (t < GPB * 2) {
        int gg = t >> 1, o = t & 1;
        float v = b2[o];
        for (int k = 0; k < 128; k++) v = fmaf(hb[gg][k], w2[k * 2 + o], v);
        outp[(size_t)(g0 + gg) * 2 + o] = v;
    }
}

extern "C" void kernel_launch(void* const* d_in, const int* in_sizes, int n_in,
                              void* d_out, int out_size, void* d_ws, size_t ws_size,
                              hipStream_t stream) {
    const float* x_c      = (const float*)d_in[0];
    const int*   ei_c     = (const int*)  d_in[1];
    const int*   batch_c  = (const int*)  d_in[2];
    const float* x_s      = (const float*)d_in[3];
    const int*   ei_s     = (const int*)  d_in[4];
    const int*   batch_s  = (const int*)  d_in[5];
    const float* Wc0      = (const float*)d_in[6];
    const float* bc0      = (const float*)d_in[7];
    const float* Wc1      = (const float*)d_in[8];
    const float* bc1      = (const float*)d_in[9];
    const float* bnc_g    = (const float*)d_in[10];
    const float* bnc_b    = (const float*)d_in[11];
    const float* bnc_m    = (const float*)d_in[12];
    const float* bnc_v    = (const float*)d_in[13];
    const float* Ws0      = (const float*)d_in[14];
    const float* bs0      = (const float*)d_in[15];
    const float* Ws1      = (const float*)d_in[16];
    const float* bs1      = (const float*)d_in[17];
    const float* bns_g    = (const float*)d_in[18];
    const float* bns_b    = (const float*)d_in[19];
    const float* bns_m    = (const float*)d_in[20];
    const float* bns_v    = (const float*)d_in[21];
    const float* fc1_w    = (const float*)d_in[22];
    const float* fc1_b    = (const float*)d_in[23];
    const float* fc2_w    = (const float*)d_in[24];
    const float* fc2_b    = (const float*)d_in[25];

    char* p = (char*)d_ws;
    auto take = [&](size_t bytes) {
        void* r = (void*)p;
        p += (bytes + 255) & ~(size_t)255;
        return r;
    };
    float* h1s    = (float*)take((size_t)NN * HD * 4);     // 102.4 MB (shared by branches)
    float* xs_c   = (float*)take((size_t)NN * 8 * 4);
    float* xs_s   = (float*)take((size_t)NN * 8 * 4);
    float* ax_c   = (float*)take((size_t)NN * 8 * 4);
    float* ax_s   = (float*)take((size_t)NN * 8 * 4);
    int*   deg_c  = (int*)  take((size_t)NN * 4);          // contiguous with deg_s (one memset)
    int*   deg_s  = (int*)  take((size_t)NN * 4);
    float* dinv_c = (float*)take((size_t)NN * 4);
    float* dinv_s = (float*)take((size_t)NN * 4);
    int*   offs_c = (int*)  take((size_t)(NN + 1) * 4);
    int*   offs_s = (int*)  take((size_t)(NN + 1) * 4);
    int*   cur_c  = (int*)  take((size_t)NN * 4);
    int*   cur_s  = (int*)  take((size_t)NN * 4);
    int*   csr_c  = (int*)  take((size_t)NE * 4);
    int*   csr_s  = (int*)  take((size_t)NE * 4);
    int*   bsum_c = (int*)  take((size_t)NB * 4);
    int*   bsum_s = (int*)  take((size_t)NB * 4);
    float* pool_c = (float*)take((size_t)NG * HD * 4);     // contiguous region: pool_c..cnt_s
    float* pool_s = (float*)take((size_t)NG * HD * 4);
    int*   cnt_c  = (int*)  take((size_t)NG * 4);
    int*   cnt_s  = (int*)  take((size_t)NG * 4);
    (void)ws_size; (void)in_sizes; (void)n_in; (void)out_size;

    hipMemsetAsync(deg_c, 0, (size_t)2 * NN * 4, stream);                       // deg_c + deg_s
    hipMemsetAsync(pool_c, 0, ((size_t)2 * NG * HD + 2 * NG) * 4, stream);      // pools + cnts

    const int* src_c = ei_c;           const int* dst_c = ei_c + NE;
    const int* src_s = ei_s;           const int* dst_s = ei_s + NE;

    // ---- merged prep (both branches in each launch) ----
    k_hist  <<<(2 * NE + 255) / 256, 256, 0, stream>>>(dst_c, dst_s, batch_c, batch_s,
                                                       deg_c, deg_s, cnt_c, cnt_s);
    k_scan1m<<<2 * NB, 256, 0, stream>>>(deg_c, deg_s, bsum_c, bsum_s, dinv_c, dinv_s);
    k_scan2m<<<2, 256, 0, stream>>>(bsum_c, bsum_s);
    k_scan3m<<<2 * NB, 256, 0, stream>>>(deg_c, deg_s, bsum_c, bsum_s,
                                         offs_c, offs_s, cur_c, cur_s);
    k_fillm <<<(2 * NE + 255) / 256, 256, 0, stream>>>(src_c, dst_c, src_s, dst_s,
                                                       cur_c, cur_s, csr_c, csr_s);
    k_prex  <<<2 * NN * 8 / 256, 256, 0, stream>>>(x_c, x_s, dinv_c, dinv_s, xs_c, xs_s);
    k_aggx2 <<<2 * NBAX, 256, 0, stream>>>(xs_c, xs_s, dinv_c, dinv_s,
                                           offs_c, offs_s, csr_c, csr_s, ax_c, ax_s);

    // ---- branch c ----
    k_gemm1m<<<NN * 32 / 256, 256, 0, stream>>>(ax_c, dinv_c, Wc0, bc0,
                                                bnc_g, bnc_b, bnc_m, bnc_v, h1s);
    k_agp   <<<NN / 64, 256, 0, stream>>>(h1s, dinv_c, offs_c, csr_c, batch_c,
                                          Wc1, bc1, bnc_g + HD, bnc_b + HD, bnc_m + HD, bnc_v + HD,
                                          pool_c);
    // ---- branch s ----
    k_gemm1m<<<NN * 32 / 256, 256, 0, stream>>>(ax_s, dinv_s, Ws0, bs0,
                                                bns_g, bns_b, bns_m, bns_v, h1s);
    k_agp   <<<NN / 64, 256, 0, stream>>>(h1s, dinv_s, offs_s, csr_s, batch_s,
                                          Ws1, bs1, bns_g + HD, bns_b + HD, bns_m + HD, bns_v + HD,
                                          pool_s);

    k_mlp<<<NG / GPB, 128, 0, stream>>>(pool_c, pool_s, cnt_c, cnt_s,
                                        fc1_w, fc1_b, fc2_w, fc2_b, (float*)d_out);
}

// Round 5
// 694.430 us; speedup vs baseline: 1.8308x; 1.8308x over previous
//
#include <hip/hip_runtime.h>

#define NN 200000
#define NE 600000
#define NG 8192
#define HD 128
#define FIN 7
#define BN_EPS 1e-5f

#define CHUNK 1024
#define NB 196          // ceil(NN / CHUNK)
#define TA 32           // nodes per k_agp tile
#define NBT (NN / TA)   // 6250 blocks per branch
#define ECAP 224        // LDS-staged csr entries per tile (mean 96, sigma ~10)

// ---------------- merged degree + graph-count histogram ----------------
__global__ void k_hist(const int* __restrict__ dstC, const int* __restrict__ dstS,
                       const int* __restrict__ batchC, const int* __restrict__ batchS,
                       int* __restrict__ degC, int* __restrict__ degS,
                       int* __restrict__ cntC, int* __restrict__ cntS) {
    int e = blockIdx.x * 256 + threadIdx.x;
    if (e < NE)            atomicAdd(&degC[dstC[e]], 1);
    else if (e < 2 * NE)   atomicAdd(&degS[dstS[e - NE]], 1);
    if (e < NN)                      atomicAdd(&cntC[batchC[e]], 1);
    else if (e >= NE && e < NE + NN) atomicAdd(&cntS[batchS[e - NE]], 1);
}

// ---------------- merged 3-phase exclusive scan (dinv folded into phase 1) ----------------
__global__ void k_scan1m(const int* __restrict__ degC, const int* __restrict__ degS,
                         int* __restrict__ bsumC, int* __restrict__ bsumS,
                         float* __restrict__ dinvC, float* __restrict__ dinvS) {
    __shared__ int sd[256];
    int t = threadIdx.x;
    int b = blockIdx.x;
    bool sBr = b >= NB;
    int bb = sBr ? b - NB : b;
    const int* deg = sBr ? degS : degC;
    float* dinv = sBr ? dinvS : dinvC;
    int* bsum = sBr ? bsumS : bsumC;
    int base = bb * CHUNK + t * 4;
    int s = 0;
#pragma unroll
    for (int j = 0; j < 4; j++) {
        int i = base + j;
        if (i < NN) {
            int d = deg[i];
            s += d;
            dinv[i] = rsqrtf((float)(d + 1));
        }
    }
    sd[t] = s; __syncthreads();
    for (int st = 128; st > 0; st >>= 1) { if (t < st) sd[t] += sd[t + st]; __syncthreads(); }
    if (t == 0) bsum[bb] = sd[0];
}

__global__ void k_scan2m(int* __restrict__ bsumC, int* __restrict__ bsumS) {
    __shared__ int sd[256];
    int* bsum = blockIdx.x ? bsumS : bsumC;
    int t = threadIdx.x;
    int v = (t < NB) ? bsum[t] : 0;
    sd[t] = v; __syncthreads();
    for (int st = 1; st < 256; st <<= 1) {
        int add = (t >= st) ? sd[t - st] : 0;
        __syncthreads();
        sd[t] += add;
        __syncthreads();
    }
    if (t < NB) bsum[t] = sd[t] - v;   // exclusive
}

__global__ void k_scan3m(const int* __restrict__ degC, const int* __restrict__ degS,
                         const int* __restrict__ bsumC, const int* __restrict__ bsumS,
                         int* __restrict__ offsC, int* __restrict__ offsS,
                         int* __restrict__ curC, int* __restrict__ curS) {
    __shared__ int sd[256];
    int t = threadIdx.x;
    int b = blockIdx.x;
    bool sBr = b >= NB;
    int bb = sBr ? b - NB : b;
    const int* deg  = sBr ? degS  : degC;
    const int* bsum = sBr ? bsumS : bsumC;
    int* offs   = sBr ? offsS : offsC;
    int* cursor = sBr ? curS  : curC;
    int base = bb * CHUNK + t * 4;
    int v[4]; int s = 0;
#pragma unroll
    for (int j = 0; j < 4; j++) { int i = base + j; v[j] = (i < NN) ? deg[i] : 0; s += v[j]; }
    sd[t] = s; __syncthreads();
    for (int st = 1; st < 256; st <<= 1) {
        int add = (t >= st) ? sd[t - st] : 0;
        __syncthreads();
        sd[t] += add;
        __syncthreads();
    }
    int run = bsum[bb] + sd[t] - s;
#pragma unroll
    for (int j = 0; j < 4; j++) {
        int i = base + j;
        if (i < NN) { offs[i] = run; cursor[i] = run; run += v[j]; }
    }
    if (bb == 0 && t == 0) offs[NN] = NE;
}

__global__ void k_fillm(const int* __restrict__ srcC, const int* __restrict__ dstC,
                        const int* __restrict__ srcS, const int* __restrict__ dstS,
                        int* __restrict__ curC, int* __restrict__ curS,
                        int* __restrict__ csrC, int* __restrict__ csrS) {
    int e = blockIdx.x * 256 + threadIdx.x;
    if (e < NE) {
        int d = dstC[e];
        int pos = atomicAdd(&curC[d], 1);
        csrC[pos] = srcC[e];
    } else if (e < 2 * NE) {
        int ee = e - NE;
        int d = dstS[ee];
        int pos = atomicAdd(&curS[d], 1);
        csrS[pos] = srcS[ee];
    }
}

// ---------------- xs = dinv * x, padded to 8 floats/row ----------------
__global__ void k_prex(const float* __restrict__ xC, const float* __restrict__ xS,
                       const float* __restrict__ dinvC, const float* __restrict__ dinvS,
                       float* __restrict__ xsC, float* __restrict__ xsS) {
    int gid = blockIdx.x * 256 + threadIdx.x;    // 2*NN*8 threads (12500 blocks exact)
    bool sBr = gid >= NN * 8;
    int lid = sBr ? gid - NN * 8 : gid;
    const float* x    = sBr ? xS    : xC;
    const float* dinv = sBr ? dinvS : dinvC;
    float*       xs   = sBr ? xsS   : xsC;
    int i = lid >> 3, f = lid & 7;
    float v = (f < FIN) ? x[(size_t)i * FIN + f] : 0.f;
    xs[lid] = v * dinv[i];
}

// ---------------- layer-1 aggregation: per-node gather of pre-scaled xs ----------------
__global__ void k_aggxm(const float* __restrict__ xsC, const float* __restrict__ xsS,
                        const float* __restrict__ dinvC, const float* __restrict__ dinvS,
                        const int* __restrict__ offsC, const int* __restrict__ offsS,
                        const int* __restrict__ csrC, const int* __restrict__ csrS,
                        float* __restrict__ axC, float* __restrict__ axS) {
    int gid = blockIdx.x * 256 + threadIdx.x;    // 2*NN*8 threads
    bool sBr = gid >= NN * 8;
    int lid = sBr ? gid - NN * 8 : gid;
    const float* xs   = sBr ? xsS   : xsC;
    const float* dinv = sBr ? dinvS : dinvC;
    const int*   offs = sBr ? offsS : offsC;
    const int*   csr  = sBr ? csrS  : csrC;
    float*       ax   = sBr ? axS   : axC;
    int i = lid >> 3, f = lid & 7;
    float v = xs[lid];
    int o1 = offs[i], o2 = offs[i + 1];
    int j = o1;
    for (; j + 2 <= o2; j += 2) {                // 2-deep pipelined
        int s0 = csr[j], s1 = csr[j + 1];
        float u0 = xs[(size_t)s0 * 8 + f];
        float u1 = xs[(size_t)s1 * 8 + f];
        v += u0; v += u1;
    }
    if (j < o2) v += xs[(size_t)csr[j] * 8 + f];
    ax[lid] = v * dinv[i];
}

// ---------------- layer-1 GEMM + BN + ReLU, output pre-scaled by dinv ----------------
__global__ __launch_bounds__(256) void k_gemm1m(
    const float* __restrict__ ax, const float* __restrict__ dinv,
    const float* __restrict__ W0, const float* __restrict__ b0,
    const float* __restrict__ gamma, const float* __restrict__ beta,
    const float* __restrict__ mean, const float* __restrict__ var,
    float* __restrict__ h1s)
{
    int gid = blockIdx.x * 256 + threadIdx.x;   // NN*32 threads (25000 blocks exact)
    int i = gid >> 5, q = (gid & 31) * 4;
    float4 a0 = *reinterpret_cast<const float4*>(&ax[(size_t)i * 8]);
    float4 a1 = *reinterpret_cast<const float4*>(&ax[(size_t)i * 8 + 4]);
    float axr[7] = { a0.x, a0.y, a0.z, a0.w, a1.x, a1.y, a1.z };
    float4 acc = *reinterpret_cast<const float4*>(&b0[q]);
#pragma unroll
    for (int k = 0; k < FIN; k++) {
        float4 w = *reinterpret_cast<const float4*>(&W0[k * HD + q]);
        acc.x = fmaf(axr[k], w.x, acc.x);
        acc.y = fmaf(axr[k], w.y, acc.y);
        acc.z = fmaf(axr[k], w.z, acc.z);
        acc.w = fmaf(axr[k], w.w, acc.w);
    }
    float di = dinv[i];
    float4 gm = *reinterpret_cast<const float4*>(&gamma[q]);
    float4 bt = *reinterpret_cast<const float4*>(&beta[q]);
    float4 mn = *reinterpret_cast<const float4*>(&mean[q]);
    float4 vr = *reinterpret_cast<const float4*>(&var[q]);
    float4 o;
    o.x = fmaxf((acc.x - mn.x) * (gm.x * rsqrtf(vr.x + BN_EPS)) + bt.x, 0.f) * di;
    o.y = fmaxf((acc.y - mn.y) * (gm.y * rsqrtf(vr.y + BN_EPS)) + bt.y, 0.f) * di;
    o.z = fmaxf((acc.z - mn.z) * (gm.z * rsqrtf(vr.z + BN_EPS)) + bt.z, 0.f) * di;
    o.w = fmaxf((acc.w - mn.w) * (gm.w * rsqrtf(vr.w + BN_EPS)) + bt.w, 0.f) * di;
    *reinterpret_cast<float4*>(&h1s[(size_t)i * HD + q]) = o;
}

// ---------------- fused: pipelined gather -> regs -> LDS, GEMM W1, BN+ReLU, mean-pool ----
// 32-node tiles, 256 threads, forced 8 waves/SIMD occupancy, 4-deep load pipelining.
__global__ __launch_bounds__(256, 8) void k_agp(
    const float* __restrict__ h1s, const float* __restrict__ dinv,
    const int* __restrict__ offs, const int* __restrict__ csr,
    const int* __restrict__ batch,
    const float* __restrict__ W1, const float* __restrict__ b1,
    const float* __restrict__ gamma, const float* __restrict__ beta,
    const float* __restrict__ mean, const float* __restrict__ var,
    float* __restrict__ pool)
{
    __shared__ float g2[TA][132];
    __shared__ int soffs[TA + 1];
    __shared__ int scsr[ECAP];
    int t = threadIdx.x;
    int nbase = blockIdx.x * TA;                 // 6250 blocks exact
    if (t <= TA) soffs[t] = offs[nbase + t];
    __syncthreads();
    int E0 = soffs[0], E1 = soffs[TA];
    int Et = E1 - E0;
    int ecap = Et < ECAP ? Et : ECAP;
    for (int j = t; j < ecap; j += 256) scsr[j] = csr[E0 + j];

    int q = t & 31, ng = t >> 5;                 // 8 node-groups x 32 feature-quads
    int n0 = ng * 4;
    int f4 = q * 4;

    // self terms (independent of scsr staging; overlaps it)
    float4 a0 = *reinterpret_cast<const float4*>(&h1s[(size_t)(nbase + n0 + 0) * HD + f4]);
    float4 a1 = *reinterpret_cast<const float4*>(&h1s[(size_t)(nbase + n0 + 1) * HD + f4]);
    float4 a2 = *reinterpret_cast<const float4*>(&h1s[(size_t)(nbase + n0 + 2) * HD + f4]);
    float4 a3 = *reinterpret_cast<const float4*>(&h1s[(size_t)(nbase + n0 + 3) * HD + f4]);
    __syncthreads();

    int e    = soffs[n0];
    int eend = soffs[n0 + 4];
    int lo = n0;

#define ACCSEL(v)                                                        \
    {                                                                    \
        while (e >= soffs[lo + 1]) ++lo;                                 \
        int rel = lo - n0;                                               \
        bool m0 = (rel == 0), m1 = (rel == 1), m2 = (rel == 2);          \
        bool m3 = (rel == 3);                                            \
        a0.x += m0 ? v.x : 0.f; a0.y += m0 ? v.y : 0.f;                  \
        a0.z += m0 ? v.z : 0.f; a0.w += m0 ? v.w : 0.f;                  \
        a1.x += m1 ? v.x : 0.f; a1.y += m1 ? v.y : 0.f;                  \
        a1.z += m1 ? v.z : 0.f; a1.w += m1 ? v.w : 0.f;                  \
        a2.x += m2 ? v.x : 0.f; a2.y += m2 ? v.y : 0.f;                  \
        a2.z += m2 ? v.z : 0.f; a2.w += m2 ? v.w : 0.f;                  \
        a3.x += m3 ? v.x : 0.f; a3.y += m3 ? v.y : 0.f;                  \
        a3.z += m3 ? v.z : 0.f; a3.w += m3 ? v.w : 0.f;                  \
        ++e;                                                             \
    }

    while (e + 4 <= eend) {
        int j = e - E0;
        int s0, s1, s2, s3;
        if (j + 4 <= ECAP) {
            s0 = scsr[j]; s1 = scsr[j + 1]; s2 = scsr[j + 2]; s3 = scsr[j + 3];
        } else {
            s0 = (j     < ECAP) ? scsr[j]     : csr[e];
            s1 = (j + 1 < ECAP) ? scsr[j + 1] : csr[e + 1];
            s2 = (j + 2 < ECAP) ? scsr[j + 2] : csr[e + 2];
            s3 = (j + 3 < ECAP) ? scsr[j + 3] : csr[e + 3];
        }
        float4 v0 = *reinterpret_cast<const float4*>(&h1s[(size_t)s0 * HD + f4]);
        float4 v1 = *reinterpret_cast<const float4*>(&h1s[(size_t)s1 * HD + f4]);
        float4 v2 = *reinterpret_cast<const float4*>(&h1s[(size_t)s2 * HD + f4]);
        float4 v3 = *reinterpret_cast<const float4*>(&h1s[(size_t)s3 * HD + f4]);
        ACCSEL(v0); ACCSEL(v1); ACCSEL(v2); ACCSEL(v3);
    }
    while (e < eend) {
        int j = e - E0;
        int s0 = (j < ECAP) ? scsr[j] : csr[e];
        float4 v0 = *reinterpret_cast<const float4*>(&h1s[(size_t)s0 * HD + f4]);
        ACCSEL(v0);
    }
#undef ACCSEL

    *reinterpret_cast<float4*>(&g2[n0 + 0][f4]) = a0;
    *reinterpret_cast<float4*>(&g2[n0 + 1][f4]) = a1;
    *reinterpret_cast<float4*>(&g2[n0 + 2][f4]) = a2;
    *reinterpret_cast<float4*>(&g2[n0 + 3][f4]) = a3;
    __syncthreads();

    // ---- phase 2: GEMM (32x128 @ 128x128), thread = 4 nodes x 4 features ----
    float acc[4][4];
#pragma unroll
    for (int a = 0; a < 4; a++)
#pragma unroll
        for (int c = 0; c < 4; c++) acc[a][c] = 0.f;

    for (int k = 0; k < 128; k += 4) {
        float ha[4][4];
#pragma unroll
        for (int a = 0; a < 4; a++) {
            float4 hv = *reinterpret_cast<const float4*>(&g2[n0 + a][k]);
            ha[a][0] = hv.x; ha[a][1] = hv.y; ha[a][2] = hv.z; ha[a][3] = hv.w;
        }
#pragma unroll
        for (int j = 0; j < 4; j++) {
            float4 w = *reinterpret_cast<const float4*>(&W1[(k + j) * HD + f4]);
#pragma unroll
            for (int a = 0; a < 4; a++) {
                acc[a][0] = fmaf(ha[a][j], w.x, acc[a][0]);
                acc[a][1] = fmaf(ha[a][j], w.y, acc[a][1]);
                acc[a][2] = fmaf(ha[a][j], w.z, acc[a][2]);
                acc[a][3] = fmaf(ha[a][j], w.w, acc[a][3]);
            }
        }
    }

    // ---- phase 3: scale by dinv_i, BN + ReLU + segmented mean-pool ----
    float4 gm = *reinterpret_cast<const float4*>(&gamma[f4]);
    float4 bt = *reinterpret_cast<const float4*>(&beta[f4]);
    float4 mn = *reinterpret_cast<const float4*>(&mean[f4]);
    float4 vr = *reinterpret_cast<const float4*>(&var[f4]);
    float4 bb = *reinterpret_cast<const float4*>(&b1[f4]);
    float Ax = gm.x * rsqrtf(vr.x + BN_EPS), Bx = (bb.x - mn.x) * Ax + bt.x;
    float Ay = gm.y * rsqrtf(vr.y + BN_EPS), By = (bb.y - mn.y) * Ay + bt.y;
    float Az = gm.z * rsqrtf(vr.z + BN_EPS), Bz = (bb.z - mn.z) * Az + bt.z;
    float Aw = gm.w * rsqrtf(vr.w + BN_EPS), Bw = (bb.w - mn.w) * Aw + bt.w;

    float sx = 0, sy = 0, sz = 0, sw = 0;
    int curg = -1;
#pragma unroll
    for (int a = 0; a < 4; a++) {
        int i = nbase + n0 + a;
        int g = batch[i];
        float sdv = dinv[i];
        float zx = fmaxf(fmaf(acc[a][0] * sdv, Ax, Bx), 0.f);
        float zy = fmaxf(fmaf(acc[a][1] * sdv, Ay, By), 0.f);
        float zz = fmaxf(fmaf(acc[a][2] * sdv, Az, Bz), 0.f);
        float zw = fmaxf(fmaf(acc[a][3] * sdv, Aw, Bw), 0.f);
        if (g != curg) {
            if (curg >= 0) {
                atomicAdd(&pool[curg * HD + f4 + 0], sx);
                atomicAdd(&pool[curg * HD + f4 + 1], sy);
                atomicAdd(&pool[curg * HD + f4 + 2], sz);
                atomicAdd(&pool[curg * HD + f4 + 3], sw);
            }
            curg = g; sx = zx; sy = zy; sz = zz; sw = zw;
        } else { sx += zx; sy += zy; sz += zz; sw += zw; }
    }
    atomicAdd(&pool[curg * HD + f4 + 0], sx);
    atomicAdd(&pool[curg * HD + f4 + 1], sy);
    atomicAdd(&pool[curg * HD + f4 + 2], sz);
    atomicAdd(&pool[curg * HD + f4 + 3], sw);
}

// ---------------- final MLP, 16 graphs per block ----------------
#define GPB 16
__global__ __launch_bounds__(128) void k_mlp(
    const float* __restrict__ pc, const float* __restrict__ ps,
    const int* __restrict__ cc, const int* __restrict__ cs,
    const float* __restrict__ w1, const float* __restrict__ b1,
    const float* __restrict__ w2, const float* __restrict__ b2,
    float* __restrict__ outp)
{
    __shared__ float xc[GPB][256];
    __shared__ float hb[GPB][128];
    int t = threadIdx.x;
    int g0 = blockIdx.x * GPB;
#pragma unroll
    for (int gg = 0; gg < GPB; gg++) {
        int g = g0 + gg;
        xc[gg][t]       = pc[g * HD + t] / fmaxf((float)cc[g], 1.f);
        xc[gg][128 + t] = ps[g * HD + t] / fmaxf((float)cs[g], 1.f);
    }
    __syncthreads();
    float acc[GPB];
#pragma unroll
    for (int gg = 0; gg < GPB; gg++) acc[gg] = b1[t];
#pragma unroll 2
    for (int k = 0; k < 256; k++) {
        float w = w1[k * HD + t];
#pragma unroll
        for (int gg = 0; gg < GPB; gg++) acc[gg] = fmaf(xc[gg][k], w, acc[gg]);
    }
#pragma unroll
    for (int gg = 0; gg < GPB; gg++) hb[gg][t] = fmaxf(acc[gg], 0.f);
    __syncthreads();
    if (t < GPB * 2) {
        int gg = t >> 1, o = t & 1;
        float v = b2[o];
        for (int k = 0; k < 128; k++) v = fmaf(hb[gg][k], w2[k * 2 + o], v);
        outp[(size_t)(g0 + gg) * 2 + o] = v;
    }
}

extern "C" void kernel_launch(void* const* d_in, const int* in_sizes, int n_in,
                              void* d_out, int out_size, void* d_ws, size_t ws_size,
                              hipStream_t stream) {
    const float* x_c      = (const float*)d_in[0];
    const int*   ei_c     = (const int*)  d_in[1];
    const int*   batch_c  = (const int*)  d_in[2];
    const float* x_s      = (const float*)d_in[3];
    const int*   ei_s     = (const int*)  d_in[4];
    const int*   batch_s  = (const int*)  d_in[5];
    const float* Wc0      = (const float*)d_in[6];
    const float* bc0      = (const float*)d_in[7];
    const float* Wc1      = (const float*)d_in[8];
    const float* bc1      = (const float*)d_in[9];
    const float* bnc_g    = (const float*)d_in[10];
    const float* bnc_b    = (const float*)d_in[11];
    const float* bnc_m    = (const float*)d_in[12];
    const float* bnc_v    = (const float*)d_in[13];
    const float* Ws0      = (const float*)d_in[14];
    const float* bs0      = (const float*)d_in[15];
    const float* Ws1      = (const float*)d_in[16];
    const float* bs1      = (const float*)d_in[17];
    const float* bns_g    = (const float*)d_in[18];
    const float* bns_b    = (const float*)d_in[19];
    const float* bns_m    = (const float*)d_in[20];
    const float* bns_v    = (const float*)d_in[21];
    const float* fc1_w    = (const float*)d_in[22];
    const float* fc1_b    = (const float*)d_in[23];
    const float* fc2_w    = (const float*)d_in[24];
    const float* fc2_b    = (const float*)d_in[25];

    char* p = (char*)d_ws;
    auto take = [&](size_t bytes) {
        void* r = (void*)p;
        p += (bytes + 255) & ~(size_t)255;
        return r;
    };
    float* h1s    = (float*)take((size_t)NN * HD * 4);     // 102.4 MB (shared by branches)
    float* xs_c   = (float*)take((size_t)NN * 8 * 4);
    float* xs_s   = (float*)take((size_t)NN * 8 * 4);
    float* ax_c   = (float*)take((size_t)NN * 8 * 4);
    float* ax_s   = (float*)take((size_t)NN * 8 * 4);
    int*   deg_c  = (int*)  take((size_t)NN * 4);          // contiguous with deg_s (one memset)
    int*   deg_s  = (int*)  take((size_t)NN * 4);
    float* dinv_c = (float*)take((size_t)NN * 4);
    float* dinv_s = (float*)take((size_t)NN * 4);
    int*   offs_c = (int*)  take((size_t)(NN + 1) * 4);
    int*   offs_s = (int*)  take((size_t)(NN + 1) * 4);
    int*   cur_c  = (int*)  take((size_t)NN * 4);
    int*   cur_s  = (int*)  take((size_t)NN * 4);
    int*   csr_c  = (int*)  take((size_t)NE * 4);
    int*   csr_s  = (int*)  take((size_t)NE * 4);
    int*   bsum_c = (int*)  take((size_t)NB * 4);
    int*   bsum_s = (int*)  take((size_t)NB * 4);
    float* pool_c = (float*)take((size_t)NG * HD * 4);     // contiguous region: pool_c..cnt_s
    float* pool_s = (float*)take((size_t)NG * HD * 4);
    int*   cnt_c  = (int*)  take((size_t)NG * 4);
    int*   cnt_s  = (int*)  take((size_t)NG * 4);
    (void)ws_size; (void)in_sizes; (void)n_in; (void)out_size;

    hipMemsetAsync(deg_c, 0, (size_t)2 * NN * 4, stream);                       // deg_c + deg_s
    hipMemsetAsync(pool_c, 0, ((size_t)2 * NG * HD + 2 * NG) * 4, stream);      // pools + cnts

    const int* src_c = ei_c;           const int* dst_c = ei_c + NE;
    const int* src_s = ei_s;           const int* dst_s = ei_s + NE;

    // ---- merged prep (both branches in each launch) ----
    k_hist  <<<(2 * NE + 255) / 256, 256, 0, stream>>>(dst_c, dst_s, batch_c, batch_s,
                                                       deg_c, deg_s, cnt_c, cnt_s);
    k_scan1m<<<2 * NB, 256, 0, stream>>>(deg_c, deg_s, bsum_c, bsum_s, dinv_c, dinv_s);
    k_scan2m<<<2, 256, 0, stream>>>(bsum_c, bsum_s);
    k_scan3m<<<2 * NB, 256, 0, stream>>>(deg_c, deg_s, bsum_c, bsum_s,
                                         offs_c, offs_s, cur_c, cur_s);
    k_fillm <<<(2 * NE + 255) / 256, 256, 0, stream>>>(src_c, dst_c, src_s, dst_s,
                                                       cur_c, cur_s, csr_c, csr_s);
    k_prex  <<<2 * NN * 8 / 256, 256, 0, stream>>>(x_c, x_s, dinv_c, dinv_s, xs_c, xs_s);
    k_aggxm <<<2 * NN * 8 / 256, 256, 0, stream>>>(xs_c, xs_s, dinv_c, dinv_s,
                                                   offs_c, offs_s, csr_c, csr_s, ax_c, ax_s);

    // ---- branch c ----
    k_gemm1m<<<NN * 32 / 256, 256, 0, stream>>>(ax_c, dinv_c, Wc0, bc0,
                                                bnc_g, bnc_b, bnc_m, bnc_v, h1s);
    k_agp   <<<NBT, 256, 0, stream>>>(h1s, dinv_c, offs_c, csr_c, batch_c,
                                      Wc1, bc1, bnc_g + HD, bnc_b + HD, bnc_m + HD, bnc_v + HD,
                                      pool_c);
    // ---- branch s ----
    k_gemm1m<<<NN * 32 / 256, 256, 0, stream>>>(ax_s, dinv_s, Ws0, bs0,
                                                bns_g, bns_b, bns_m, bns_v, h1s);
    k_agp   <<<NBT, 256, 0, stream>>>(h1s, dinv_s, offs_s, csr_s, batch_s,
                                      Ws1, bs1, bns_g + HD, bns_b + HD, bns_m + HD, bns_v + HD,
                                      pool_s);

    k_mlp<<<NG / GPB, 128, 0, stream>>>(pool_c, pool_s, cnt_c, cnt_s,
                                        fc1_w, fc1_b, fc2_w, fc2_b, (float*)d_out);
}

// Round 6
// 528.259 us; speedup vs baseline: 2.4067x; 1.3146x over previous
//
#include <hip/hip_runtime.h>

#define NN 200000
#define NE 600000
#define NG 8192
#define HD 128
#define FIN 7
#define BN_EPS 1e-5f

#define CHUNK 1024
#define NB 196          // ceil(NN / CHUNK)
#define TA 64           // nodes per k_agp tile
#define NBT (NN / TA)   // 3125 blocks per branch
#define ECAP 320        // LDS-staged csr entries per tile (mean 192, sigma ~14)

// ---------------- merged degree + graph-count histogram ----------------
__global__ void k_hist(const int* __restrict__ dstC, const int* __restrict__ dstS,
                       const int* __restrict__ batchC, const int* __restrict__ batchS,
                       int* __restrict__ degC, int* __restrict__ degS,
                       int* __restrict__ cntC, int* __restrict__ cntS) {
    int e = blockIdx.x * 256 + threadIdx.x;
    if (e < NE)            atomicAdd(&degC[dstC[e]], 1);
    else if (e < 2 * NE)   atomicAdd(&degS[dstS[e - NE]], 1);
    if (e < NN)                      atomicAdd(&cntC[batchC[e]], 1);
    else if (e >= NE && e < NE + NN) atomicAdd(&cntS[batchS[e - NE]], 1);
}

// ---------------- scan phase 1 + dinv + xs = x*dinv (padded to 8) ----------------
__global__ void k_scan1m(const int* __restrict__ degC, const int* __restrict__ degS,
                         int* __restrict__ bsumC, int* __restrict__ bsumS,
                         float* __restrict__ dinvC, float* __restrict__ dinvS,
                         const float* __restrict__ xC, const float* __restrict__ xS,
                         float* __restrict__ xsC, float* __restrict__ xsS) {
    __shared__ int sd[256];
    int t = threadIdx.x;
    int b = blockIdx.x;
    bool sBr = b >= NB;
    int bb = sBr ? b - NB : b;
    const int* deg = sBr ? degS : degC;
    const float* x = sBr ? xS : xC;
    float* dinv = sBr ? dinvS : dinvC;
    float* xs   = sBr ? xsS : xsC;
    int* bsum = sBr ? bsumS : bsumC;
    int base = bb * CHUNK + t * 4;
    int s = 0;
#pragma unroll
    for (int j = 0; j < 4; j++) {
        int i = base + j;
        if (i < NN) {
            int d = deg[i];
            s += d;
            float di = rsqrtf((float)(d + 1));
            dinv[i] = di;
            float4 v0, v1;
            v0.x = x[(size_t)i * FIN + 0] * di;
            v0.y = x[(size_t)i * FIN + 1] * di;
            v0.z = x[(size_t)i * FIN + 2] * di;
            v0.w = x[(size_t)i * FIN + 3] * di;
            v1.x = x[(size_t)i * FIN + 4] * di;
            v1.y = x[(size_t)i * FIN + 5] * di;
            v1.z = x[(size_t)i * FIN + 6] * di;
            v1.w = 0.f;
            *reinterpret_cast<float4*>(&xs[(size_t)i * 8])     = v0;
            *reinterpret_cast<float4*>(&xs[(size_t)i * 8 + 4]) = v1;
        }
    }
    sd[t] = s; __syncthreads();
    for (int st = 128; st > 0; st >>= 1) { if (t < st) sd[t] += sd[t + st]; __syncthreads(); }
    if (t == 0) bsum[bb] = sd[0];
}

__global__ void k_scan2m(int* __restrict__ bsumC, int* __restrict__ bsumS) {
    __shared__ int sd[256];
    int* bsum = blockIdx.x ? bsumS : bsumC;
    int t = threadIdx.x;
    int v = (t < NB) ? bsum[t] : 0;
    sd[t] = v; __syncthreads();
    for (int st = 1; st < 256; st <<= 1) {
        int add = (t >= st) ? sd[t - st] : 0;
        __syncthreads();
        sd[t] += add;
        __syncthreads();
    }
    if (t < NB) bsum[t] = sd[t] - v;   // exclusive
}

__global__ void k_scan3m(const int* __restrict__ degC, const int* __restrict__ degS,
                         const int* __restrict__ bsumC, const int* __restrict__ bsumS,
                         int* __restrict__ offsC, int* __restrict__ offsS,
                         int* __restrict__ curC, int* __restrict__ curS) {
    __shared__ int sd[256];
    int t = threadIdx.x;
    int b = blockIdx.x;
    bool sBr = b >= NB;
    int bb = sBr ? b - NB : b;
    const int* deg  = sBr ? degS  : degC;
    const int* bsum = sBr ? bsumS : bsumC;
    int* offs   = sBr ? offsS : offsC;
    int* cursor = sBr ? curS  : curC;
    int base = bb * CHUNK + t * 4;
    int v[4]; int s = 0;
#pragma unroll
    for (int j = 0; j < 4; j++) { int i = base + j; v[j] = (i < NN) ? deg[i] : 0; s += v[j]; }
    sd[t] = s; __syncthreads();
    for (int st = 1; st < 256; st <<= 1) {
        int add = (t >= st) ? sd[t - st] : 0;
        __syncthreads();
        sd[t] += add;
        __syncthreads();
    }
    int run = bsum[bb] + sd[t] - s;
#pragma unroll
    for (int j = 0; j < 4; j++) {
        int i = base + j;
        if (i < NN) { offs[i] = run; cursor[i] = run; run += v[j]; }
    }
    if (bb == 0 && t == 0) offs[NN] = NE;
}

__global__ void k_fillm(const int* __restrict__ srcC, const int* __restrict__ dstC,
                        const int* __restrict__ srcS, const int* __restrict__ dstS,
                        int* __restrict__ curC, int* __restrict__ curS,
                        int* __restrict__ csrC, int* __restrict__ csrS) {
    int e = blockIdx.x * 256 + threadIdx.x;
    if (e < NE) {
        int d = dstC[e];
        int pos = atomicAdd(&curC[d], 1);
        csrC[pos] = srcC[e];
    } else if (e < 2 * NE) {
        int ee = e - NE;
        int d = dstS[ee];
        int pos = atomicAdd(&curS[d], 1);
        csrS[pos] = srcS[ee];
    }
}

// ---------------- layer-1 aggregation -> axd rows: [ax0..ax6, dinv_i] ----------------
__global__ void k_aggxm(const float* __restrict__ xsC, const float* __restrict__ xsS,
                        const float* __restrict__ dinvC, const float* __restrict__ dinvS,
                        const int* __restrict__ offsC, const int* __restrict__ offsS,
                        const int* __restrict__ csrC, const int* __restrict__ csrS,
                        float* __restrict__ axdC, float* __restrict__ axdS) {
    int gid = blockIdx.x * 256 + threadIdx.x;    // 2*NN*8 threads (12500 blocks exact)
    bool sBr = gid >= NN * 8;
    int lid = sBr ? gid - NN * 8 : gid;
    const float* xs   = sBr ? xsS   : xsC;
    const float* dinv = sBr ? dinvS : dinvC;
    const int*   offs = sBr ? offsS : offsC;
    const int*   csr  = sBr ? csrS  : csrC;
    float*       axd  = sBr ? axdS  : axdC;
    int i = lid >> 3, f = lid & 7;
    float v = xs[lid];
    int o1 = offs[i], o2 = offs[i + 1];
    int j = o1;
    for (; j + 2 <= o2; j += 2) {                // 2-deep pipelined
        int s0 = csr[j], s1 = csr[j + 1];
        float u0 = xs[(size_t)s0 * 8 + f];
        float u1 = xs[(size_t)s1 * 8 + f];
        v += u0; v += u1;
    }
    if (j < o2) v += xs[(size_t)csr[j] * 8 + f];
    float di = dinv[i];
    axd[lid] = (f == 7) ? di : v * di;           // lane 7 carries dinv_i
}

// ------ per-source contribution: a += relu(ax_s . W0' + c') * dinv_s (4 features) ------
__device__ __forceinline__ void src_contrib(const float* __restrict__ axd, int s,
                                            const float4* wp, const float4 c4, float4& a) {
    float4 r0 = *reinterpret_cast<const float4*>(&axd[(size_t)s * 8]);
    float4 r1 = *reinterpret_cast<const float4*>(&axd[(size_t)s * 8 + 4]);
    float axr[7] = { r0.x, r0.y, r0.z, r0.w, r1.x, r1.y, r1.z };
    float4 y = c4;
#pragma unroll
    for (int k = 0; k < FIN; k++) {
        y.x = fmaf(axr[k], wp[k].x, y.x);
        y.y = fmaf(axr[k], wp[k].y, y.y);
        y.z = fmaf(axr[k], wp[k].z, y.z);
        y.w = fmaf(axr[k], wp[k].w, y.w);
    }
    a.x = fmaf(fmaxf(y.x, 0.f), r1.w, a.x);
    a.y = fmaf(fmaxf(y.y, 0.f), r1.w, a.y);
    a.z = fmaf(fmaxf(y.z, 0.f), r1.w, a.z);
    a.w = fmaf(fmaxf(y.w, 0.f), r1.w, a.w);
}

// ---------------- fused: recompute-gather -> LDS, GEMM W1, BN+ReLU, mean-pool ----------
// h1 is recomputed per edge from the 32 B axd row (BN1 folded into W0'/c'), so the
// gather reads 32 B from a 6.4 MB L2-resident buffer instead of 512 B from 102 MB.
// Both branches in one dispatch (blocks [0,NBT) = c, [NBT,2*NBT) = s).
__global__ __launch_bounds__(256, 4) void k_agp2(
    const float* __restrict__ axdC, const float* __restrict__ axdS,
    const float* __restrict__ dinvC, const float* __restrict__ dinvS,
    const int* __restrict__ offsC, const int* __restrict__ offsS,
    const int* __restrict__ csrC, const int* __restrict__ csrS,
    const int* __restrict__ batchC, const int* __restrict__ batchS,
    const float* __restrict__ Wc0, const float* __restrict__ bc0,
    const float* __restrict__ bncG, const float* __restrict__ bncB,
    const float* __restrict__ bncM, const float* __restrict__ bncV,
    const float* __restrict__ Wc1, const float* __restrict__ bc1,
    const float* __restrict__ Ws0, const float* __restrict__ bs0,
    const float* __restrict__ bnsG, const float* __restrict__ bnsB,
    const float* __restrict__ bnsM, const float* __restrict__ bnsV,
    const float* __restrict__ Ws1, const float* __restrict__ bs1,
    float* __restrict__ poolC, float* __restrict__ poolS)
{
    __shared__ float g2[TA][132];
    __shared__ int soffs[TA + 1];
    __shared__ int scsr[ECAP];
    int b = blockIdx.x;
    bool sBr = b >= NBT;
    int bb = sBr ? b - NBT : b;
    const float* axd  = sBr ? axdS  : axdC;
    const float* dinv = sBr ? dinvS : dinvC;
    const int*  offs  = sBr ? offsS : offsC;
    const int*  csr   = sBr ? csrS  : csrC;
    const int*  batch = sBr ? batchS : batchC;
    const float* W0   = sBr ? Ws0 : Wc0;
    const float* b0   = sBr ? bs0 : bc0;
    const float* bnG  = sBr ? bnsG : bncG;
    const float* bnB  = sBr ? bnsB : bncB;
    const float* bnM  = sBr ? bnsM : bncM;
    const float* bnV  = sBr ? bnsV : bncV;
    const float* W1   = sBr ? Ws1 : Wc1;
    const float* b1   = sBr ? bs1 : bc1;
    float* pool       = sBr ? poolS : poolC;

    int t = threadIdx.x;
    int nbase = bb * TA;
    if (t <= TA) soffs[t] = offs[nbase + t];
    __syncthreads();
    int E0 = soffs[0], E1 = soffs[TA];
    int ecap = (E1 - E0) < ECAP ? (E1 - E0) : ECAP;
    for (int j = t; j < ecap; j += 256) scsr[j] = csr[E0 + j];

    int q = t & 31, ng = t >> 5;                 // 8 node-groups x 32 feature-quads
    int f4 = q * 4, n0 = ng * 8;

    // ---- fold BN1 into W0' (wp) and c' (c4) for this thread's 4 columns ----
    float4 gm = *reinterpret_cast<const float4*>(&bnG[f4]);
    float4 vr = *reinterpret_cast<const float4*>(&bnV[f4]);
    float4 mn = *reinterpret_cast<const float4*>(&bnM[f4]);
    float4 bt = *reinterpret_cast<const float4*>(&bnB[f4]);
    float4 bb0 = *reinterpret_cast<const float4*>(&b0[f4]);
    float4 gsc;
    gsc.x = gm.x * rsqrtf(vr.x + BN_EPS);
    gsc.y = gm.y * rsqrtf(vr.y + BN_EPS);
    gsc.z = gm.z * rsqrtf(vr.z + BN_EPS);
    gsc.w = gm.w * rsqrtf(vr.w + BN_EPS);
    float4 wp[FIN];
#pragma unroll
    for (int k = 0; k < FIN; k++) {
        float4 w = *reinterpret_cast<const float4*>(&W0[k * HD + f4]);
        wp[k] = make_float4(w.x * gsc.x, w.y * gsc.y, w.z * gsc.z, w.w * gsc.w);
    }
    float4 c4 = make_float4((bb0.x - mn.x) * gsc.x + bt.x,
                            (bb0.y - mn.y) * gsc.y + bt.y,
                            (bb0.z - mn.z) * gsc.z + bt.z,
                            (bb0.w - mn.w) * gsc.w + bt.w);
    __syncthreads();                             // scsr ready

    // ---- phase 1: recompute-gather agg tile (unscaled by dinv_i; folded in phase 3) ----
#pragma unroll
    for (int n = 0; n < 8; n++) {
        int ln = n0 + n;
        float4 a = make_float4(0.f, 0.f, 0.f, 0.f);
        src_contrib(axd, nbase + ln, wp, c4, a);         // self loop
        int e = soffs[ln], ee = soffs[ln + 1];
        for (; e < ee; e++) {
            int j = e - E0;
            int s = (j < ECAP) ? scsr[j] : csr[e];
            src_contrib(axd, s, wp, c4, a);
        }
        *reinterpret_cast<float4*>(&g2[ln][f4]) = a;
    }
    __syncthreads();

    // ---- phase 2: GEMM (64x128 @ 128x128), thread = 8 nodes x 4 features ----
    float acc[8][4];
#pragma unroll
    for (int a = 0; a < 8; a++)
#pragma unroll
        for (int c = 0; c < 4; c++) acc[a][c] = 0.f;

    for (int k = 0; k < 128; k += 4) {
        float ha[8][4];
#pragma unroll
        for (int a = 0; a < 8; a++) {
            float4 hv = *reinterpret_cast<const float4*>(&g2[n0 + a][k]);
            ha[a][0] = hv.x; ha[a][1] = hv.y; ha[a][2] = hv.z; ha[a][3] = hv.w;
        }
#pragma unroll
        for (int j = 0; j < 4; j++) {
            float4 w = *reinterpret_cast<const float4*>(&W1[(k + j) * HD + f4]);
#pragma unroll
            for (int a = 0; a < 8; a++) {
                acc[a][0] = fmaf(ha[a][j], w.x, acc[a][0]);
                acc[a][1] = fmaf(ha[a][j], w.y, acc[a][1]);
                acc[a][2] = fmaf(ha[a][j], w.z, acc[a][2]);
                acc[a][3] = fmaf(ha[a][j], w.w, acc[a][3]);
            }
        }
    }

    // ---- phase 3: scale by dinv_i, BN2 + ReLU + segmented mean-pool ----
    float4 gm2 = *reinterpret_cast<const float4*>(&bnG[HD + f4]);
    float4 bt2 = *reinterpret_cast<const float4*>(&bnB[HD + f4]);
    float4 mn2 = *reinterpret_cast<const float4*>(&bnM[HD + f4]);
    float4 vr2 = *reinterpret_cast<const float4*>(&bnV[HD + f4]);
    float4 bb1 = *reinterpret_cast<const float4*>(&b1[f4]);
    float Ax = gm2.x * rsqrtf(vr2.x + BN_EPS), Bx = (bb1.x - mn2.x) * Ax + bt2.x;
    float Ay = gm2.y * rsqrtf(vr2.y + BN_EPS), By = (bb1.y - mn2.y) * Ay + bt2.y;
    float Az = gm2.z * rsqrtf(vr2.z + BN_EPS), Bz = (bb1.z - mn2.z) * Az + bt2.z;
    float Aw = gm2.w * rsqrtf(vr2.w + BN_EPS), Bw = (bb1.w - mn2.w) * Aw + bt2.w;

    float sx = 0, sy = 0, sz = 0, sw = 0;
    int curg = -1;
#pragma unroll
    for (int a = 0; a < 8; a++) {
        int i = nbase + n0 + a;
        int g = batch[i];
        float sdv = dinv[i];
        float zx = fmaxf(fmaf(acc[a][0] * sdv, Ax, Bx), 0.f);
        float zy = fmaxf(fmaf(acc[a][1] * sdv, Ay, By), 0.f);
        float zz = fmaxf(fmaf(acc[a][2] * sdv, Az, Bz), 0.f);
        float zw = fmaxf(fmaf(acc[a][3] * sdv, Aw, Bw), 0.f);
        if (g != curg) {
            if (curg >= 0) {
                atomicAdd(&pool[curg * HD + f4 + 0], sx);
                atomicAdd(&pool[curg * HD + f4 + 1], sy);
                atomicAdd(&pool[curg * HD + f4 + 2], sz);
                atomicAdd(&pool[curg * HD + f4 + 3], sw);
            }
            curg = g; sx = zx; sy = zy; sz = zz; sw = zw;
        } else { sx += zx; sy += zy; sz += zz; sw += zw; }
    }
    atomicAdd(&pool[curg * HD + f4 + 0], sx);
    atomicAdd(&pool[curg * HD + f4 + 1], sy);
    atomicAdd(&pool[curg * HD + f4 + 2], sz);
    atomicAdd(&pool[curg * HD + f4 + 3], sw);
}

// ---------------- final MLP, 16 graphs per block ----------------
#define GPB 16
__global__ __launch_bounds__(128) void k_mlp(
    const float* __restrict__ pc, const float* __restrict__ ps,
    const int* __restrict__ cc, const int* __restrict__ cs,
    const float* __restrict__ w1, const float* __restrict__ b1,
    const float* __restrict__ w2, const float* __restrict__ b2,
    float* __restrict__ outp)
{
    __shared__ float xc[GPB][256];
    __shared__ float hb[GPB][128];
    int t = threadIdx.x;
    int g0 = blockIdx.x * GPB;
#pragma unroll
    for (int gg = 0; gg < GPB; gg++) {
        int g = g0 + gg;
        xc[gg][t]       = pc[g * HD + t] / fmaxf((float)cc[g], 1.f);
        xc[gg][128 + t] = ps[g * HD + t] / fmaxf((float)cs[g], 1.f);
    }
    __syncthreads();
    float acc[GPB];
#pragma unroll
    for (int gg = 0; gg < GPB; gg++) acc[gg] = b1[t];
#pragma unroll 2
    for (int k = 0; k < 256; k++) {
        float w = w1[k * HD + t];
#pragma unroll
        for (int gg = 0; gg < GPB; gg++) acc[gg] = fmaf(xc[gg][k], w, acc[gg]);
    }
#pragma unroll
    for (int gg = 0; gg < GPB; gg++) hb[gg][t] = fmaxf(acc[gg], 0.f);
    __syncthreads();
    if (t < GPB * 2) {
        int gg = t >> 1, o = t & 1;
        float v = b2[o];
        for (int k = 0; k < 128; k++) v = fmaf(hb[gg][k], w2[k * 2 + o], v);
        outp[(size_t)(g0 + gg) * 2 + o] = v;
    }
}

extern "C" void kernel_launch(void* const* d_in, const int* in_sizes, int n_in,
                              void* d_out, int out_size, void* d_ws, size_t ws_size,
                              hipStream_t stream) {
    const float* x_c      = (const float*)d_in[0];
    const int*   ei_c     = (const int*)  d_in[1];
    const int*   batch_c  = (const int*)  d_in[2];
    const float* x_s      = (const float*)d_in[3];
    const int*   ei_s     = (const int*)  d_in[4];
    const int*   batch_s  = (const int*)  d_in[5];
    const float* Wc0      = (const float*)d_in[6];
    const float* bc0      = (const float*)d_in[7];
    const float* Wc1      = (const float*)d_in[8];
    const float* bc1      = (const float*)d_in[9];
    const float* bnc_g    = (const float*)d_in[10];
    const float* bnc_b    = (const float*)d_in[11];
    const float* bnc_m    = (const float*)d_in[12];
    const float* bnc_v    = (const float*)d_in[13];
    const float* Ws0      = (const float*)d_in[14];
    const float* bs0      = (const float*)d_in[15];
    const float* Ws1      = (const float*)d_in[16];
    const float* bs1      = (const float*)d_in[17];
    const float* bns_g    = (const float*)d_in[18];
    const float* bns_b    = (const float*)d_in[19];
    const float* bns_m    = (const float*)d_in[20];
    const float* bns_v    = (const float*)d_in[21];
    const float* fc1_w    = (const float*)d_in[22];
    const float* fc1_b    = (const float*)d_in[23];
    const float* fc2_w    = (const float*)d_in[24];
    const float* fc2_b    = (const float*)d_in[25];

    char* p = (char*)d_ws;
    auto take = [&](size_t bytes) {
        void* r = (void*)p;
        p += (bytes + 255) & ~(size_t)255;
        return r;
    };
    float* xs_c   = (float*)take((size_t)NN * 8 * 4);
    float* xs_s   = (float*)take((size_t)NN * 8 * 4);
    float* axd_c  = (float*)take((size_t)NN * 8 * 4);
    float* axd_s  = (float*)take((size_t)NN * 8 * 4);
    int*   deg_c  = (int*)  take((size_t)NN * 4);          // contiguous with deg_s (one memset)
    int*   deg_s  = (int*)  take((size_t)NN * 4);
    float* dinv_c = (float*)take((size_t)NN * 4);
    float* dinv_s = (float*)take((size_t)NN * 4);
    int*   offs_c = (int*)  take((size_t)(NN + 1) * 4);
    int*   offs_s = (int*)  take((size_t)(NN + 1) * 4);
    int*   cur_c  = (int*)  take((size_t)NN * 4);
    int*   cur_s  = (int*)  take((size_t)NN * 4);
    int*   csr_c  = (int*)  take((size_t)NE * 4);
    int*   csr_s  = (int*)  take((size_t)NE * 4);
    int*   bsum_c = (int*)  take((size_t)NB * 4);
    int*   bsum_s = (int*)  take((size_t)NB * 4);
    float* pool_c = (float*)take((size_t)NG * HD * 4);     // contiguous region: pool_c..cnt_s
    float* pool_s = (float*)take((size_t)NG * HD * 4);
    int*   cnt_c  = (int*)  take((size_t)NG * 4);
    int*   cnt_s  = (int*)  take((size_t)NG * 4);
    (void)ws_size; (void)in_sizes; (void)n_in; (void)out_size;

    hipMemsetAsync(deg_c, 0, (size_t)2 * NN * 4, stream);                       // deg_c + deg_s
    hipMemsetAsync(pool_c, 0, ((size_t)2 * NG * HD + 2 * NG) * 4, stream);      // pools + cnts

    const int* src_c = ei_c;           const int* dst_c = ei_c + NE;
    const int* src_s = ei_s;           const int* dst_s = ei_s + NE;

    k_hist  <<<(2 * NE + 255) / 256, 256, 0, stream>>>(dst_c, dst_s, batch_c, batch_s,
                                                       deg_c, deg_s, cnt_c, cnt_s);
    k_scan1m<<<2 * NB, 256, 0, stream>>>(deg_c, deg_s, bsum_c, bsum_s, dinv_c, dinv_s,
                                         x_c, x_s, xs_c, xs_s);
    k_scan2m<<<2, 256, 0, stream>>>(bsum_c, bsum_s);
    k_scan3m<<<2 * NB, 256, 0, stream>>>(deg_c, deg_s, bsum_c, bsum_s,
                                         offs_c, offs_s, cur_c, cur_s);
    k_fillm <<<(2 * NE + 255) / 256, 256, 0, stream>>>(src_c, dst_c, src_s, dst_s,
                                                       cur_c, cur_s, csr_c, csr_s);
    k_aggxm <<<2 * NN * 8 / 256, 256, 0, stream>>>(xs_c, xs_s, dinv_c, dinv_s,
                                                   offs_c, offs_s, csr_c, csr_s, axd_c, axd_s);

    k_agp2<<<2 * NBT, 256, 0, stream>>>(axd_c, axd_s, dinv_c, dinv_s,
                                        offs_c, offs_s, csr_c, csr_s, batch_c, batch_s,
                                        Wc0, bc0, bnc_g, bnc_b, bnc_m, bnc_v, Wc1, bc1,
                                        Ws0, bs0, bns_g, bns_b, bns_m, bns_v, Ws1, bs1,
                                        pool_c, pool_s);

    k_mlp<<<NG / GPB, 128, 0, stream>>>(pool_c, pool_s, cnt_c, cnt_s,
                                        fc1_w, fc1_b, fc2_w, fc2_b, (float*)d_out);
}